// Round 5
// baseline (238.907 us; speedup 1.0000x reference)
//
#include <hip/hip_runtime.h>
#include <hip/hip_bf16.h>

#define L 512
#define CS 256
#define CZ 128
#define LN_EPS 1e-5f

typedef _Float16 f16_t;
typedef f16_t f16x8 __attribute__((ext_vector_type(8)));
typedef float f32x4 __attribute__((ext_vector_type(4)));
typedef float f32x16 __attribute__((ext_vector_type(16)));

// ---- Kernel PREP -----------------------------------------------------------
// Per-block (i = blockIdx.x): embed + LN -> s_out, u2 (CHUNK-MAJOR f16:
// u2[c>>3][i][c&7]), zrow = u@W1 + b, zcol = u@W2.
// Spare duties: blocks 0..127 build w3c (chunk-major W3^T f16), blocks
// 128..391 build tab[cp*66+rp] = Ecp[cp] + Erp[rp].
__global__ __launch_bounds__(256) void k_prep(
    const int* __restrict__ seq, const int* __restrict__ cid,
    const int* __restrict__ ridx,
    const float* __restrict__ Eaa, const float* __restrict__ Epos,
    const float* __restrict__ Ech, const float* __restrict__ lnw,
    const float* __restrict__ lnb, const float* __restrict__ Wp,
    const float* __restrict__ bp, const float* __restrict__ Ecp,
    const float* __restrict__ Erp,
    float* __restrict__ s_out, f16_t* __restrict__ u2,
    float* __restrict__ zrow, float* __restrict__ zcol,
    f16_t* __restrict__ w3c, float* __restrict__ tab)
{
    __shared__ float su[CS];
    __shared__ float red[8];
    const int i = blockIdx.x;
    const int c = threadIdx.x;

    if (i < 128) {
        w3c[(c >> 3) * (CZ * 8) + i * 8 + (c & 7)] = (f16_t)Wp[(2 * CS + c) * CZ + i];
    } else if (i < 128 + 264) {
        const int b2 = i - 128;
        if (c < CZ)
            tab[b2 * CZ + c] = Ecp[(b2 / 66) * CZ + c] + Erp[(b2 % 66) * CZ + c];
    }

    const int sq = seq[i], ri = ridx[i], ci = cid[i];
    const float v = Eaa[sq * CS + c] + Epos[ri * CS + c] + Ech[ci * CS + c];
    s_out[i * CS + c] = v;

    float s1 = v, s2 = v * v;
    #pragma unroll
    for (int o = 32; o > 0; o >>= 1) {
        s1 += __shfl_down(s1, o, 64);
        s2 += __shfl_down(s2, o, 64);
    }
    const int wv = c >> 6, lane = c & 63;
    if (lane == 0) { red[wv * 2] = s1; red[wv * 2 + 1] = s2; }
    __syncthreads();
    const float S  = red[0] + red[2] + red[4] + red[6];
    const float SS = red[1] + red[3] + red[5] + red[7];
    const float mu  = S * (1.0f / CS);
    const float var = SS * (1.0f / CS) - mu * mu;
    const float rs  = rsqrtf(var + LN_EPS);
    const float u   = (v - mu) * rs * lnw[c] + lnb[c];
    u2[(c >> 3) * (L * 8) + i * 8 + (c & 7)] = (f16_t)u;
    su[c] = u;
    __syncthreads();

    const int z = c & 127;
    const int half = c >> 7;  // 0 -> zrow(W1), 1 -> zcol(W2)
    const float* W = Wp + half * CS * CZ + z;
    float a0 = 0, a1 = 0, a2 = 0, a3 = 0;
    #pragma unroll 8
    for (int cc = 0; cc < CS; cc += 4) {
        a0 += su[cc + 0] * W[(cc + 0) * CZ];
        a1 += su[cc + 1] * W[(cc + 1) * CZ];
        a2 += su[cc + 2] * W[(cc + 2) * CZ];
        a3 += su[cc + 3] * W[(cc + 3) * CZ];
    }
    const float acc = (a0 + a1) + (a2 + a3);
    if (half) zcol[i * CZ + z] = acc;
    else      zrow[i * CZ + z] = acc + bp[z];
}

// ---- Kernel PAIR -----------------------------------------------------------
// Grid (16,64): block = 8 i x 32 j x 128 z, 4 waves = 4 z-quarters.
// Store-bound kernel (134 MB out, 21 us floor): maximize store-latency
// hiding via occupancy. Single acc chain (one i at a time) keeps live VGPRs
// ~120 -> __launch_bounds__(256,4) = 16 waves/CU, 1024 blocks co-resident.
// u tiles in LDS (chunk-major, conflict-free b128 + broadcasts); A = W3^T
// slice persistent in 64 VGPR. Normal stores: per (i,j,wave) the 8 dwordx4
// merge to one 128B line in L2 (NT stores broke this in R3: +50% WRITE).
__global__ __launch_bounds__(256, 4) void k_pair(
    const f16_t* __restrict__ u2, const f16_t* __restrict__ w3c,
    const float* __restrict__ zrow, const float* __restrict__ zcol,
    const float* __restrict__ tab,
    const int* __restrict__ cid, const int* __restrict__ ridx,
    float* __restrict__ zout)
{
    __shared__ f16_t lds[(1024 + 256) * 8];  // u_j tile (16KB) + u_i tile (4KB)
    f16x8* lj = (f16x8*)lds;
    f16x8* li = ((f16x8*)lds) + 1024;

    const int t = threadIdx.x;
    const int lane = t & 63, wave = t >> 6;
    const int m32 = lane & 31, h = lane >> 5;
    const int j0 = blockIdx.x * 32, i0 = blockIdx.y * 8;
    const int z0 = wave * 32;

    const f16x8* pu = (const f16x8*)u2;    // [32 chunks][512 rows]
    const f16x8* pw = (const f16x8*)w3c;   // [32 chunks][128 z]

    // stage LDS tiles (contiguous src + dst)
    li[t] = pu[(t >> 3) * L + i0 + (t & 7)];     // t = ch*8 + ii
    #pragma unroll
    for (int rep = 0; rep < 4; ++rep) {
        const int un = rep * 256 + t;            // un = ch*32 + jj
        lj[un] = pu[(un >> 5) * L + j0 + (un & 31)];
    }

    // A fragments: W3T[z0+m32][(ch*2+h)*8 .. +7], kept in 64 VGPRs
    f16x8 A[16];
    #pragma unroll
    for (int ch = 0; ch < 16; ++ch)
        A[ch] = pw[(ch * 2 + h) * CZ + z0 + m32];

    const int j = j0 + m32;
    const int cj = cid[j], rj = ridx[j];
    f32x4 ZC[4];
    #pragma unroll
    for (int g = 0; g < 4; ++g)
        ZC[g] = *(const f32x4*)&zcol[j * CZ + z0 + 8 * g + 4 * h];

    __syncthreads();

    for (int rg = 0; rg < 8; ++rg) {
        const int i = i0 + rg;

        f32x16 acc = {0,0,0,0,0,0,0,0,0,0,0,0,0,0,0,0};
        #pragma unroll
        for (int ch = 0; ch < 16; ++ch) {
            const int cb = (ch * 2 + h);
            f16x8 uj = lj[cb * 32 + m32];        // conflict-free b128
            f16x8 ui = li[cb * 8 + rg];          // broadcast
            acc = __builtin_amdgcn_mfma_f32_32x32x16_f16(A[ch], ui * uj, acc, 0, 0, 0);
        }

        const int ci = cid[i], ri = ridx[i];     // wave-uniform -> scalar
        int d = ri - rj;
        d = d < -32 ? -32 : (d > 32 ? 32 : d);
        const int rp = (ci == cj) ? (d + 32) : 65;
        const int idx = (ci * 2 + cj) * 66 + rp;
        float* orow = zout + ((size_t)i * L + j) * CZ;
        #pragma unroll
        for (int g = 0; g < 4; ++g) {
            const int zq = z0 + 8 * g + 4 * h;
            f32x4 zr = *(const f32x4*)&zrow[i * CZ + zq];
            f32x4 tb = *(const f32x4*)&tab[idx * CZ + zq];
            f32x4 o;
            o[0] = acc[4 * g + 0] + zr[0] + ZC[g][0] + tb[0];
            o[1] = acc[4 * g + 1] + zr[1] + ZC[g][1] + tb[1];
            o[2] = acc[4 * g + 2] + zr[2] + ZC[g][2] + tb[2];
            o[3] = acc[4 * g + 3] + zr[3] + ZC[g][3] + tb[3];
            *(f32x4*)&orow[zq] = o;
        }
    }
}

extern "C" void kernel_launch(void* const* d_in, const int* in_sizes, int n_in,
                              void* d_out, int out_size, void* d_ws, size_t ws_size,
                              hipStream_t stream) {
    const int*   seq  = (const int*)d_in[0];
    const int*   cid  = (const int*)d_in[1];
    const int*   ridx = (const int*)d_in[2];
    const float* Eaa  = (const float*)d_in[3];
    const float* Epos = (const float*)d_in[4];
    const float* Ech  = (const float*)d_in[5];
    const float* Ecp  = (const float*)d_in[6];
    const float* Erp  = (const float*)d_in[7];
    const float* Wp   = (const float*)d_in[8];
    const float* bp   = (const float*)d_in[9];
    const float* lnw  = (const float*)d_in[10];
    const float* lnb  = (const float*)d_in[11];

    float* out   = (float*)d_out;
    float* s_out = out;
    float* zout  = out + L * CS;

    char* ws = (char*)d_ws;
    f16_t* u2   = (f16_t*)ws;                 // 256 KB, chunk-major
    f16_t* w3c  = (f16_t*)(ws + 262144);      // 64 KB, chunk-major
    float* zrow = (float*)(ws + 327680);      // 256 KB
    float* zcol = (float*)(ws + 589824);      // 256 KB
    float* tab  = (float*)(ws + 851968);      // 132 KB

    hipLaunchKernelGGL(k_prep, dim3(L), dim3(256), 0, stream,
                       seq, cid, ridx, Eaa, Epos, Ech, lnw, lnb, Wp, bp,
                       Ecp, Erp, s_out, u2, zrow, zcol, w3c, tab);
    hipLaunchKernelGGL(k_pair, dim3(16, 64), dim3(256), 0, stream,
                       u2, w3c, zrow, zcol, tab, cid, ridx, zout);
}

// Round 6
// 174.866 us; speedup vs baseline: 1.3662x; 1.3662x over previous
//
#include <hip/hip_runtime.h>
#include <hip/hip_bf16.h>

#define L 512
#define CS 256
#define CZ 128
#define LN_EPS 1e-5f

typedef _Float16 f16_t;
typedef f16_t f16x8 __attribute__((ext_vector_type(8)));
typedef float f32x4 __attribute__((ext_vector_type(4)));

// ---- Kernel PREP -----------------------------------------------------------
// Per-block (i = blockIdx.x): embed + LN -> s_out, u2 (CHUNK-MAJOR f16:
// u2[c>>3][i][c&7]), zrow = u@W1 + b, zcol = u@W2.
// Spare duties: blocks 0..127 build w3c (chunk-major W3^T f16), blocks
// 128..391 build tab[cp*66+rp] = Ecp[cp] + Erp[rp].
__global__ __launch_bounds__(256) void k_prep(
    const int* __restrict__ seq, const int* __restrict__ cid,
    const int* __restrict__ ridx,
    const float* __restrict__ Eaa, const float* __restrict__ Epos,
    const float* __restrict__ Ech, const float* __restrict__ lnw,
    const float* __restrict__ lnb, const float* __restrict__ Wp,
    const float* __restrict__ bp, const float* __restrict__ Ecp,
    const float* __restrict__ Erp,
    float* __restrict__ s_out, f16_t* __restrict__ u2,
    float* __restrict__ zrow, float* __restrict__ zcol,
    f16_t* __restrict__ w3c, float* __restrict__ tab)
{
    __shared__ float su[CS];
    __shared__ float red[8];
    const int i = blockIdx.x;
    const int c = threadIdx.x;

    if (i < 128) {
        w3c[(c >> 3) * (CZ * 8) + i * 8 + (c & 7)] = (f16_t)Wp[(2 * CS + c) * CZ + i];
    } else if (i < 128 + 264) {
        const int b2 = i - 128;
        if (c < CZ)
            tab[b2 * CZ + c] = Ecp[(b2 / 66) * CZ + c] + Erp[(b2 % 66) * CZ + c];
    }

    const int sq = seq[i], ri = ridx[i], ci = cid[i];
    const float v = Eaa[sq * CS + c] + Epos[ri * CS + c] + Ech[ci * CS + c];
    s_out[i * CS + c] = v;

    float s1 = v, s2 = v * v;
    #pragma unroll
    for (int o = 32; o > 0; o >>= 1) {
        s1 += __shfl_down(s1, o, 64);
        s2 += __shfl_down(s2, o, 64);
    }
    const int wv = c >> 6, lane = c & 63;
    if (lane == 0) { red[wv * 2] = s1; red[wv * 2 + 1] = s2; }
    __syncthreads();
    const float S  = red[0] + red[2] + red[4] + red[6];
    const float SS = red[1] + red[3] + red[5] + red[7];
    const float mu  = S * (1.0f / CS);
    const float var = SS * (1.0f / CS) - mu * mu;
    const float rs  = rsqrtf(var + LN_EPS);
    const float u   = (v - mu) * rs * lnw[c] + lnb[c];
    u2[(c >> 3) * (L * 8) + i * 8 + (c & 7)] = (f16_t)u;
    su[c] = u;
    __syncthreads();

    const int z = c & 127;
    const int half = c >> 7;  // 0 -> zrow(W1), 1 -> zcol(W2)
    const float* W = Wp + half * CS * CZ + z;
    float a0 = 0, a1 = 0, a2 = 0, a3 = 0;
    #pragma unroll 8
    for (int cc = 0; cc < CS; cc += 4) {
        a0 += su[cc + 0] * W[(cc + 0) * CZ];
        a1 += su[cc + 1] * W[(cc + 1) * CZ];
        a2 += su[cc + 2] * W[(cc + 2) * CZ];
        a3 += su[cc + 3] * W[(cc + 3) * CZ];
    }
    const float acc = (a0 + a1) + (a2 + a3);
    if (half) zcol[i * CZ + z] = acc;
    else      zrow[i * CZ + z] = acc + bp[z];
}

// ---- Kernel PAIR -----------------------------------------------------------
// Store-bound (134 MB out, ~21 us floor). Block = 512 threads (8 waves),
// tile 8i x 32j x 128z; wave w owns z-segment [16w,16w+16).
// mfma_f32_16x16x32_f16: A = W3^T slice, only 8 frags = 32 VGPR (the 32z
// tile's 64-VGPR A is what made the R5 allocator spill at cap 128).
// Dual-i x dual-jt = 4 independent MFMA chains. Live ~90 VGPR ->
// __launch_bounds__(512,4): 2 blocks/CU = 16 waves/CU for store latency
// hiding. LDS staging layout measured conflict-free (R5: BANK_CONFLICT=0).
// Normal stores: L2 merges partial lines (NT broke this in R3, +50% WRITE).
__global__ __launch_bounds__(512, 4) void k_pair(
    const f16_t* __restrict__ u2, const f16_t* __restrict__ w3c,
    const float* __restrict__ zrow, const float* __restrict__ zcol,
    const float* __restrict__ tab,
    const int* __restrict__ cid, const int* __restrict__ ridx,
    float* __restrict__ zout)
{
    __shared__ f16_t lds[(1024 + 256) * 8];  // u_j tile (16KB) + u_i tile (4KB)
    f16x8* lj = (f16x8*)lds;
    f16x8* li = ((f16x8*)lds) + 1024;

    const int t = threadIdx.x;
    const int lane = t & 63, wave = t >> 6;
    const int m = lane & 15, q = lane >> 4;
    const int j0 = blockIdx.x * 32, i0 = blockIdx.y * 8;
    const int zseg = wave * 16;
    const int zq = zseg + q * 4;             // this lane's 4 z's

    const f16x8* pu = (const f16x8*)u2;      // [32 chunks][512 rows]
    const f16x8* pw = (const f16x8*)w3c;     // [32 chunks][128 z]

    // stage LDS tiles (contiguous src + dst)
    if (t < 256) li[t] = pu[(t >> 3) * L + i0 + (t & 7)];   // t = ch*8 + ii
    #pragma unroll
    for (int rep = 0; rep < 2; ++rep) {
        const int un = rep * 512 + t;                       // un = ch*32 + jj
        lj[un] = pu[(un >> 5) * L + j0 + (un & 31)];
    }

    // A fragments: A[k32] = W3T[zseg+m][k32*32 + q*8 .. +7]  (32 VGPR)
    f16x8 A[8];
    #pragma unroll
    for (int k32 = 0; k32 < 8; ++k32)
        A[k32] = pw[(k32 * 4 + q) * CZ + zseg + m];

    // per-lane j's for the two j-subtiles
    const int ja = j0 + m, jb = j0 + 16 + m;
    const int cja = cid[ja], rja = ridx[ja];
    const int cjb = cid[jb], rjb = ridx[jb];
    f32x4 ZCa = *(const f32x4*)&zcol[ja * CZ + zq];
    f32x4 ZCb = *(const f32x4*)&zcol[jb * CZ + zq];

    __syncthreads();

    #pragma unroll
    for (int ig = 0; ig < 4; ++ig) {
        const int i_0 = i0 + ig * 2, i_1 = i_0 + 1;

        // epilogue operands first (independent of MFMA chain)
        const int ci0 = cid[i_0], ri0 = ridx[i_0];
        const int ci1 = cid[i_1], ri1 = ridx[i_1];
        int d;
        d = ri0 - rja; d = d < -32 ? -32 : (d > 32 ? 32 : d);
        const int x0a = ((ci0 * 2 + cja) * 66) + ((ci0 == cja) ? (d + 32) : 65);
        d = ri0 - rjb; d = d < -32 ? -32 : (d > 32 ? 32 : d);
        const int x0b = ((ci0 * 2 + cjb) * 66) + ((ci0 == cjb) ? (d + 32) : 65);
        d = ri1 - rja; d = d < -32 ? -32 : (d > 32 ? 32 : d);
        const int x1a = ((ci1 * 2 + cja) * 66) + ((ci1 == cja) ? (d + 32) : 65);
        d = ri1 - rjb; d = d < -32 ? -32 : (d > 32 ? 32 : d);
        const int x1b = ((ci1 * 2 + cjb) * 66) + ((ci1 == cjb) ? (d + 32) : 65);
        f32x4 zr0 = *(const f32x4*)&zrow[i_0 * CZ + zq];
        f32x4 zr1 = *(const f32x4*)&zrow[i_1 * CZ + zq];
        f32x4 t0a = *(const f32x4*)&tab[x0a * CZ + zq];
        f32x4 t0b = *(const f32x4*)&tab[x0b * CZ + zq];
        f32x4 t1a = *(const f32x4*)&tab[x1a * CZ + zq];
        f32x4 t1b = *(const f32x4*)&tab[x1b * CZ + zq];

        f32x4 a0a = {0,0,0,0}, a0b = {0,0,0,0};
        f32x4 a1a = {0,0,0,0}, a1b = {0,0,0,0};
        #pragma unroll
        for (int k32 = 0; k32 < 8; ++k32) {
            const int cb = k32 * 4 + q;
            f16x8 uja = lj[cb * 32 + m];        // conflict-free b128
            f16x8 ujb = lj[cb * 32 + 16 + m];   // conflict-free b128
            f16x8 ui0 = li[cb * 8 + ig * 2];    // broadcast
            f16x8 ui1 = li[cb * 8 + ig * 2 + 1];
            a0a = __builtin_amdgcn_mfma_f32_16x16x32_f16(A[k32], ui0 * uja, a0a, 0, 0, 0);
            a0b = __builtin_amdgcn_mfma_f32_16x16x32_f16(A[k32], ui0 * ujb, a0b, 0, 0, 0);
            a1a = __builtin_amdgcn_mfma_f32_16x16x32_f16(A[k32], ui1 * uja, a1a, 0, 0, 0);
            a1b = __builtin_amdgcn_mfma_f32_16x16x32_f16(A[k32], ui1 * ujb, a1b, 0, 0, 0);
        }

        float* r0 = zout + ((size_t)i_0 * L + j0 + m) * CZ + zq;
        float* r1 = zout + ((size_t)i_1 * L + j0 + m) * CZ + zq;
        f32x4 o;
        o = a0a + zr0 + ZCa + t0a; *(f32x4*)r0 = o;
        o = a0b + zr0 + ZCb + t0b; *(f32x4*)(r0 + 16 * CZ) = o;
        o = a1a + zr1 + ZCa + t1a; *(f32x4*)r1 = o;
        o = a1b + zr1 + ZCb + t1b; *(f32x4*)(r1 + 16 * CZ) = o;
    }
}

extern "C" void kernel_launch(void* const* d_in, const int* in_sizes, int n_in,
                              void* d_out, int out_size, void* d_ws, size_t ws_size,
                              hipStream_t stream) {
    const int*   seq  = (const int*)d_in[0];
    const int*   cid  = (const int*)d_in[1];
    const int*   ridx = (const int*)d_in[2];
    const float* Eaa  = (const float*)d_in[3];
    const float* Epos = (const float*)d_in[4];
    const float* Ech  = (const float*)d_in[5];
    const float* Ecp  = (const float*)d_in[6];
    const float* Erp  = (const float*)d_in[7];
    const float* Wp   = (const float*)d_in[8];
    const float* bp   = (const float*)d_in[9];
    const float* lnw  = (const float*)d_in[10];
    const float* lnb  = (const float*)d_in[11];

    float* out   = (float*)d_out;
    float* s_out = out;
    float* zout  = out + L * CS;

    char* ws = (char*)d_ws;
    f16_t* u2   = (f16_t*)ws;                 // 256 KB, chunk-major
    f16_t* w3c  = (f16_t*)(ws + 262144);      // 64 KB, chunk-major
    float* zrow = (float*)(ws + 327680);      // 256 KB
    float* zcol = (float*)(ws + 589824);      // 256 KB
    float* tab  = (float*)(ws + 851968);      // 132 KB

    hipLaunchKernelGGL(k_prep, dim3(L), dim3(256), 0, stream,
                       seq, cid, ridx, Eaa, Epos, Ech, lnw, lnb, Wp, bp,
                       Ecp, Erp, s_out, u2, zrow, zcol, w3c, tab);
    hipLaunchKernelGGL(k_pair, dim3(16, 64), dim3(512), 0, stream,
                       u2, w3c, zrow, zcol, tab, cid, ridx, zout);
}